// Round 6
// baseline (355.535 us; speedup 1.0000x reference)
//
#include <hip/hip_runtime.h>

#define F 1024
#define S 128
#define H 16
#define D 64
#define NCHUNK 16    // 1024 / 64 (global chunk layout; K-loop uses BK=32 = half-chunks)

typedef short bf16x8 __attribute__((ext_vector_type(8)));
typedef float f32x4  __attribute__((ext_vector_type(4)));

// ws: xs2[128 bg][16 ch][2048 units] (B-tiles: rows = 2 batches' s, k-major)
//     wb2[ 8 hg][16 ch][2048 units] (A-tiles: rows = 2 heads' [Wq;Wk], k-major)
// unit(kc,row) = kc*256 + row ; kc in [0,8) (8 bf16 of k each), row in [0,256)
// => a BK=32 tile t is units [t*1024, (t+1)*1024) : kc' = t*4..t*4+3  (contiguous 16 KB)
#define XS_UNITS ((size_t)128 * NCHUNK * 2048)
#define WB_UNITS ((size_t)8 * NCHUNK * 2048)
#define WS_NEED ((XS_UNITS + WB_UNITS) * 16)

#define MAIN_LDS_BYTES (8192 * 16 + 8 * 128 * 4 + 128 * 4)

__device__ __forceinline__ unsigned short f2bf(float f) {
    unsigned u = __float_as_uint(f);
    u += 0x7fffu + ((u >> 16) & 1u);   // round-to-nearest-even
    return (unsigned short)(u >> 16);
}

__device__ __forceinline__ uint4 pack8(const float* f) {
    uint4 u;
    u.x = (unsigned)f2bf(f[0]) | ((unsigned)f2bf(f[1]) << 16);
    u.y = (unsigned)f2bf(f[2]) | ((unsigned)f2bf(f[3]) << 16);
    u.z = (unsigned)f2bf(f[4]) | ((unsigned)f2bf(f[5]) << 16);
    u.w = (unsigned)f2bf(f[6]) | ((unsigned)f2bf(f[7]) << 16);
    return u;
}

typedef __attribute__((address_space(1))) const unsigned int as1_u32;
typedef __attribute__((address_space(3))) unsigned int as3_u32;

__device__ __forceinline__ void async_cp16(const uint4* g, uint4* l) {
    __builtin_amdgcn_global_load_lds((as1_u32*)g, (as3_u32*)l, 16, 0, 0);
}

__device__ __forceinline__ void bar()   { __builtin_amdgcn_s_barrier(); }
__device__ __forceinline__ void sb0()   { __builtin_amdgcn_sched_barrier(0); }

template<int N> __device__ __forceinline__ void vmw() {
    asm volatile("s_waitcnt vmcnt(%0)" :: "n"(N));
}

// ---------------- prep: fp32 -> bf16, k-major tiles; direct coalesced transpose (no LDS) ----------------
__global__ void prep(const float* __restrict__ x,
                     const float* __restrict__ Wq,
                     const float* __restrict__ Wk,
                     uint4* __restrict__ xs,
                     uint4* __restrict__ wb)
{
    const int tid = threadIdx.x;
    const int blk = blockIdx.x;
    if (blk < 4096) {
        // x tile: (b, ch). unit (kc, s) <- x[b][ch*64 + kc*8 + jj][s], jj=0..7.
        const int b = blk >> 4, ch = blk & 15;
        const float* xb = x + ((size_t)b * F + ch * 64) * S;
        uint4* dst = xs + ((size_t)(b >> 1) * NCHUNK + ch) * 2048 + (b & 1) * 128;
#pragma unroll
        for (int j = 0; j < 4; ++j) {
            const int u  = tid + j * 256;
            const int kc = u >> 7;
            const int s  = u & 127;
            const float* rp = xb + (size_t)(kc * 8) * S + s;
            float f[8];
#pragma unroll
            for (int jj = 0; jj < 8; ++jj) f[jj] = rp[jj * S];
            dst[kc * 256 + s] = pack8(f);
        }
    } else {
        // W tile: (h, ch) -> unit = kc*256 + (h&1)*128 + m ; m<64 -> Wq row, else Wk row
        const int blk2 = blk - 4096;
        const int h = blk2 >> 4, ch = blk2 & 15;
        uint4* dst = wb + ((size_t)(h >> 1) * NCHUNK + ch) * 2048 + (h & 1) * 128;
#pragma unroll
        for (int j = 0; j < 4; ++j) {
            const int u  = tid + j * 256;
            const int kc = u >> 7;
            const int m  = u & 127;
            const float* srcp = (m < 64)
                ? (Wq + (size_t)(h * D + m) * F + ch * 64 + kc * 8)
                : (Wk + (size_t)(h * D + m - 64) * F + ch * 64 + kc * 8);
            float f[8];
            float4 a = ((const float4*)srcp)[0];
            float4 c = ((const float4*)srcp)[1];
            f[0] = a.x; f[1] = a.y; f[2] = a.z; f[3] = a.w;
            f[4] = c.x; f[5] = c.y; f[6] = c.z; f[7] = c.w;
            dst[kc * 256 + m] = pack8(f);
        }
    }
}

// ---------------- main kernel: BK=32, 3-buffer, 1-barrier-per-tile pipeline ----------------
// buf b occupies units [b*2048, b*2048+2048): A in [0,1024) (kc*256+row), B in [1024,2048).
template<int BUF>
__device__ __forceinline__ void stage32(uint4* mat, const uint4* wbase, const uint4* xbase,
                                        int t, int wv, int lane) {
    uint4* la = mat + BUF * 2048 + wv * 128;
    const uint4* ga = wbase + (size_t)t * 1024 + wv * 128;
    async_cp16(ga + lane,      la);
    async_cp16(ga + 64 + lane, la + 64);
    uint4* lb = mat + BUF * 2048 + 1024 + wv * 128;
    const uint4* gb = xbase + (size_t)t * 1024 + wv * 128;
    async_cp16(gb + lane,      lb);
    async_cp16(gb + 64 + lane, lb + 64);
}

// Ledger (4 loads/wave/tile, 2-deep prefetch):
//  - entering tile t (after prev bar): buf[t%3] staged+drained+published; stage(t+1) maybe in flight.
//  - tile t issues stage(t+2) -> buf[(t+2)%3] (holds t-1; all waves' t-1 reads done before prev bar).
//  - end of tile t: vmw<4> drains stage(t+1) (leaves stage(t+2)); bar publishes t+1.
//  - tails: t=30 ends vmw<0> (drains stage(31)); t=31 ends at __syncthreads (full drain).
template<int CUR, int SMODE, int WEND>
__device__ __forceinline__ void ktile3(uint4* mat, const uint4* wbase, const uint4* xbase,
                                       int t, int wv, int lane, int wm, int wn, int q, int l15,
                                       f32x4 (&acc)[8][4])
{
    constexpr int NXT = (CUR + 2) % 3;
    const int ab = CUR * 2048 + q * 256 + wm * 128 + l15;
    const int bb = CUR * 2048 + 1024 + q * 256 + wn * 64 + l15;
    bf16x8 b[4], a[8];
#pragma unroll
    for (int j = 0; j < 4; ++j) b[j] = *(const bf16x8*)&mat[bb + j * 16];
#pragma unroll
    for (int i = 0; i < 8; ++i) a[i] = *(const bf16x8*)&mat[ab + i * 16];
    if constexpr (SMODE) stage32<NXT>(mat, wbase, xbase, t + 2, wv, lane);
    sb0();
    __builtin_amdgcn_s_setprio(1);
#pragma unroll
    for (int i = 0; i < 8; ++i)
#pragma unroll
        for (int j = 0; j < 4; ++j)
            acc[i][j] = __builtin_amdgcn_mfma_f32_16x16x32_bf16(a[i], b[j], acc[i][j], 0, 0, 0);
    __builtin_amdgcn_s_setprio(0);
    sb0();
    if constexpr (WEND == 4)      { vmw<4>(); bar(); sb0(); }
    else if constexpr (WEND == 0) { vmw<0>(); bar(); sb0(); }
}

// ---------------- main: 256x256x1024 GEMM (2 heads x 2 batches) + pair-parallel attention epilogue ----------------
__launch_bounds__(512, 2)
__global__ void attn_main(const float* __restrict__ x,
                          const uint4* __restrict__ xs,
                          const uint4* __restrict__ wb,
                          const float* __restrict__ bq,
                          const float* __restrict__ bk,
                          const float* __restrict__ Wo,
                          const float* __restrict__ bo,
                          float* __restrict__ out)
{
    (void)x;
    extern __shared__ char smraw[];
    uint4* mat   = (uint4*)smraw;                       // 8192 units; K-loop uses first 6144 (3 bufs)
    float* wpart = (float*)(smraw + 8192 * 16);         // [8][128]

    const int tid  = threadIdx.x;
    const int lane = tid & 63;
    const int wv   = tid >> 6;
    const int l15  = lane & 15;
    const int q    = lane >> 4;
    const int wm   = wv >> 2;      // 2 waves rows
    const int wn   = wv & 3;       // 4 waves cols

    // XCD-aware swizzle: 1024 blocks, 8 XCDs; per XCD 16 bg x 8 hg
    const int g    = blockIdx.x;
    const int xcd  = g & 7;
    const int slot = g >> 3;
    const int bg   = xcd * 16 + (slot & 15);   // batch-pair [0,128)
    const int hg   = slot >> 4;                // head-pair  [0,8)

    const uint4* wbase = wb + (size_t)hg * NCHUNK * 2048;
    const uint4* xbase = xs + (size_t)bg * NCHUNK * 2048;

    f32x4 acc[8][4];
#pragma unroll
    for (int mi = 0; mi < 8; ++mi)
#pragma unroll
        for (int ni = 0; ni < 4; ++ni) acc[mi][ni] = (f32x4){0.f, 0.f, 0.f, 0.f};

    // prologue: stage tiles 0,1; drain tile 0 (vmw<4> leaves stage(1)); publish.
    stage32<0>(mat, wbase, xbase, 0, wv, lane);
    stage32<1>(mat, wbase, xbase, 1, wv, lane);
    vmw<4>();
    bar(); sb0();

#pragma unroll 1
    for (int i = 0; i < 10; ++i) {
        ktile3<0, 1, 4>(mat, wbase, xbase, 3 * i,     wv, lane, wm, wn, q, l15, acc);
        ktile3<1, 1, 4>(mat, wbase, xbase, 3 * i + 1, wv, lane, wm, wn, q, l15, acc);
        ktile3<2, 1, 4>(mat, wbase, xbase, 3 * i + 2, wv, lane, wm, wn, q, l15, acc);
    }
    ktile3<0, 0, 0>(mat, wbase, xbase, 30, wv, lane, wm, wn, q, l15, acc);
    ktile3<1, 0, -1>(mat, wbase, xbase, 31, wv, lane, wm, wn, q, l15, acc);

    __syncthreads();

    // C-write: +bias, bf16, write 4 combos' Qs/Ks into LDS (combo c, 2048 units each)
    {
        unsigned short* m16 = (unsigned short*)mat;
        const int hglobw = hg * 2 + wm;
#pragma unroll
        for (int rt = 0; rt < 8; ++rt) {
            const int mh0   = rt * 16 + q * 4;          // rows mh0..mh0+3 (within head's [Wq;Wk])
            const int d0    = mh0 & 63;
            const int kbase = (mh0 < 64) ? 0 : 1024;
            float bias4[4];
#pragma unroll
            for (int rr = 0; rr < 4; ++rr)
                bias4[rr] = (mh0 < 64) ? bq[hglobw * D + d0 + rr] : bk[hglobw * D + d0 + rr];
#pragma unroll
            for (int ct = 0; ct < 4; ++ct) {
                const int col = wn * 64 + ct * 16 + l15;
                const int bj  = col >> 7;
                const int s   = col & 127;
                const int c   = wm * 2 + bj;
                unsigned long long pv = 0;
#pragma unroll
                for (int rr = 0; rr < 4; ++rr)
                    pv |= (unsigned long long)f2bf(acc[rt][ct][rr] + bias4[rr]) << (16 * rr);
                const int unit = c * 2048 + kbase + s * 8 + ((d0 >> 3) ^ (s & 7));
                *(unsigned long long*)&m16[unit * 8 + (d0 & 7)] = pv;   // 8B-aligned (d0&7 in {0,4})
            }
        }
    }
    __syncthreads();

    // ---- pair-parallel epilogue: waves {2c,2c+1} own combo c; all combos concurrent ----
    const int ce   = ((wv >> 2) << 1) | ((wv >> 1) & 1);   // this wave's combo
    const int half = wv & 1;                               // s-row half within combo
    const int qb = ce * 2048;
    const int kb = ce * 2048 + 1024;
    const int bglob = bg * 2 + (ce & 1);
    const int hglob = hg * 2 + (ce >> 1);

    // phase 2: scores for s-rows [half*64, +64), all 128 t
    f32x4 p[4][8];
#pragma unroll
    for (int mt = 0; mt < 4; ++mt)
#pragma unroll
        for (int nt = 0; nt < 8; ++nt) p[mt][nt] = (f32x4){0.f, 0.f, 0.f, 0.f};
#pragma unroll
    for (int ks = 0; ks < 2; ++ks) {
        const int kcq = ks * 4 + q;
        bf16x8 a2[4], b2[8];
#pragma unroll
        for (int mt = 0; mt < 4; ++mt) {
            const int row = half * 64 + mt * 16 + l15;
            a2[mt] = *(const bf16x8*)&mat[qb + row * 8 + (kcq ^ (row & 7))];
        }
#pragma unroll
        for (int nt = 0; nt < 8; ++nt) {
            const int trow = nt * 16 + l15;
            b2[nt] = *(const bf16x8*)&mat[kb + trow * 8 + (kcq ^ (trow & 7))];
        }
#pragma unroll
        for (int mt = 0; mt < 4; ++mt)
#pragma unroll
            for (int nt = 0; nt < 8; ++nt)
                p[mt][nt] = __builtin_amdgcn_mfma_f32_16x16x32_bf16(a2[mt], b2[nt], p[mt][nt], 0, 0, 0);
    }

    // phase-5 loads issued EARLY (hidden under softmax): coalesced uint4 from xs, chunk ch = hglob
    const int ell = half * 64 + lane;
    const int kc5 = ell >> 4;
    const int sg5 = ell & 15;
    const uint4* xsrc = xbase + (size_t)hglob * 2048 + kc5 * 256 + (ce & 1) * 128 + sg5 * 8;
    uint4 xu[8];
#pragma unroll
    for (int jj = 0; jj < 8; ++jj) xu[jj] = xsrc[jj];

    // phases 3+4: softmax (no max-sub; scores ~N(0,1), clamp insurance) + fold Wo
    float pw[8];
#pragma unroll
    for (int nt = 0; nt < 8; ++nt) pw[nt] = 0.f;
#pragma unroll
    for (int mt = 0; mt < 4; ++mt) {
#pragma unroll
        for (int rr = 0; rr < 4; ++rr) {
            const int srow = half * 64 + mt * 16 + q * 4 + rr;
            float e[8];
            float l = 0.f;
#pragma unroll
            for (int nt = 0; nt < 8; ++nt) {
                e[nt] = __expf(fminf(p[mt][nt][rr] * 0.125f, 80.f));   // 1/TEMP = 1/8
                l += e[nt];
            }
#pragma unroll
            for (int off = 1; off < 16; off <<= 1) l += __shfl_xor(l, off);
            const float cw = Wo[srow] / l;
#pragma unroll
            for (int nt = 0; nt < 8; ++nt) pw[nt] = fmaf(cw, e[nt], pw[nt]);
        }
    }
#pragma unroll
    for (int nt = 0; nt < 8; ++nt) {
        pw[nt] += __shfl_xor(pw[nt], 16);
        pw[nt] += __shfl_xor(pw[nt], 32);
    }
    if (q == 0) {
#pragma unroll
        for (int nt = 0; nt < 8; ++nt) wpart[wv * 128 + nt * 16 + l15] = pw[nt];
    }
    __syncthreads();

    // phase 5: out[bglob, hglob*64 + kc5*8 + e] = sum_s w[s] * x_bf16 + bo  (x from regs)
    {
        const float* w0 = wpart + 2 * ce * 128;
        const float* w1 = w0 + 128;
        float acc8[8];
#pragma unroll
        for (int e = 0; e < 8; ++e) acc8[e] = 0.f;
#pragma unroll
        for (int jj = 0; jj < 8; ++jj) {
            const int s = sg5 * 8 + jj;
            const float w = w0[s] + w1[s];
            const unsigned* du = (const unsigned*)&xu[jj];
#pragma unroll
            for (int dw = 0; dw < 4; ++dw) {
                const unsigned v = du[dw];
                acc8[dw * 2 + 0] = fmaf(__uint_as_float(v << 16), w, acc8[dw * 2 + 0]);
                acc8[dw * 2 + 1] = fmaf(__uint_as_float(v & 0xffff0000u), w, acc8[dw * 2 + 1]);
            }
        }
#pragma unroll
        for (int e = 0; e < 8; ++e) {
#pragma unroll
            for (int off = 1; off < 16; off <<= 1)
                acc8[e] += __shfl_xor(acc8[e], off);
        }
        if (sg5 < 8)
            out[(size_t)bglob * F + hglob * D + kc5 * 8 + sg5] = acc8[sg5] + bo[0];
    }
}

// ---------------- fallback (self-contained) if ws too small ----------------
struct SmemT {
    uint4 mat[2048];
    float wpart[4][S];
    float wfin[S];
};

__launch_bounds__(256, 4)
__global__ void attn_fallback(const float* __restrict__ x,
                              const float* __restrict__ Wq,
                              const float* __restrict__ bq,
                              const float* __restrict__ Wk,
                              const float* __restrict__ bk,
                              const float* __restrict__ Wo,
                              const float* __restrict__ bo,
                              float* __restrict__ out)
{
    __shared__ SmemT sm;
    const int tid  = threadIdx.x;
    const int lane = tid & 63;
    const int wv   = tid >> 6;
    const int l15  = lane & 15;
    const int q    = lane >> 4;

    const int g    = blockIdx.x;
    const int xcd  = g & 7;
    const int slot = g >> 3;
    const int hg   = slot >> 7;
    const int r0   = slot & 127;
    const int b    = xcd * 32 + (r0 >> 2);
    const int h    = hg * 4 + (r0 & 3);

    const float* xb  = x  + (size_t)b * (F * S);
    const float* wqh = Wq + (size_t)h * D * F;
    const float* wkh = Wk + (size_t)h * D * F;

    const int m0 = (wv & 1) * 64;
    const int n0 = (wv >> 1) * 64;

    f32x4 acc[4][4];
#pragma unroll
    for (int mt = 0; mt < 4; ++mt)
#pragma unroll
        for (int nt = 0; nt < 4; ++nt) acc[mt][nt] = (f32x4){0.f, 0.f, 0.f, 0.f};

    const int mq  = tid >> 2;
    const int kq  = tid & 3;
    const int s0x = (tid & 63) * 2;
    const int iq  = tid >> 6;

    for (int ch = 0; ch < NCHUNK; ++ch) {
        const int c0 = ch * 64;
        __syncthreads();
        {
            const int key = mq & 7;
            float f[16];
            const float4* srcq = (const float4*)(wqh + (size_t)mq * F + (c0 + kq * 16));
#pragma unroll
            for (int j = 0; j < 4; ++j) {
                float4 v = srcq[j];
                f[4*j] = v.x; f[4*j+1] = v.y; f[4*j+2] = v.z; f[4*j+3] = v.w;
            }
            sm.mat[mq * 8 + ((kq * 2    ) ^ key)] = pack8(f);
            sm.mat[mq * 8 + ((kq * 2 + 1) ^ key)] = pack8(f + 8);
            const float4* srck = (const float4*)(wkh + (size_t)mq * F + (c0 + kq * 16));
#pragma unroll
            for (int j = 0; j < 4; ++j) {
                float4 v = srck[j];
                f[4*j] = v.x; f[4*j+1] = v.y; f[4*j+2] = v.z; f[4*j+3] = v.w;
            }
            sm.mat[(64 + mq) * 8 + ((kq * 2    ) ^ key)] = pack8(f);
            sm.mat[(64 + mq) * 8 + ((kq * 2 + 1) ^ key)] = pack8(f + 8);
        }
        {
            const float* src = xb + (size_t)(c0 + iq * 16) * S + s0x;
            float fa[8], fb[8];
#pragma unroll
            for (int grp = 0; grp < 2; ++grp) {
#pragma unroll
                for (int j = 0; j < 8; ++j) {
                    float2 v = *(const float2*)(src + (size_t)(grp * 8 + j) * S);
                    fa[j] = v.x; fb[j] = v.y;
                }
                const int kc = iq * 2 + grp;
                sm.mat[1024 + (s0x    ) * 8 + (kc ^ ((s0x    ) & 7))] = pack8(fa);
                sm.mat[1024 + (s0x + 1) * 8 + (kc ^ ((s0x + 1) & 7))] = pack8(fb);
            }
        }
        __syncthreads();
#pragma unroll
        for (int ks = 0; ks < 2; ++ks) {
            bf16x8 af[4], br[4];
#pragma unroll
            for (int mt = 0; mt < 4; ++mt) {
                const int row = m0 + mt * 16 + l15;
                af[mt] = *(const bf16x8*)&sm.mat[row * 8 + ((ks * 4 + q) ^ (row & 7))];
            }
#pragma unroll
            for (int nt = 0; nt < 4; ++nt) {
                const int row = n0 + nt * 16 + l15;
                br[nt] = *(const bf16x8*)&sm.mat[1024 + row * 8 + ((ks * 4 + q) ^ (row & 7))];
            }
#pragma unroll
            for (int mt = 0; mt < 4; ++mt)
#pragma unroll
                for (int nt = 0; nt < 4; ++nt)
                    acc[mt][nt] = __builtin_amdgcn_mfma_f32_16x16x32_bf16(
                        af[mt], br[nt], acc[mt][nt], 0, 0, 0);
        }
    }

    __syncthreads();
    {
        unsigned short* m16 = (unsigned short*)sm.mat;
#pragma unroll
        for (int mt = 0; mt < 4; ++mt) {
#pragma unroll
            for (int rr = 0; rr < 4; ++rr) {
                const int m = m0 + mt * 16 + q * 4 + rr;
                const int d = m & 63;
                const float bias = (m < 64) ? bq[h * D + d] : bk[h * D + d];
                const int base = (m < 64) ? 0 : 8192;
#pragma unroll
                for (int nt = 0; nt < 4; ++nt) {
                    const int s = n0 + nt * 16 + l15;
                    const float v = acc[mt][nt][rr] + bias;
                    const int unit = s * 8 + (((d >> 3)) ^ (s & 7));
                    m16[base + unit * 8 + (d & 7)] = f2bf(v);
                }
            }
        }
    }
    __syncthreads();

    f32x4 p[2][8];
#pragma unroll
    for (int mt = 0; mt < 2; ++mt)
#pragma unroll
        for (int nt = 0; nt < 8; ++nt) p[mt][nt] = (f32x4){0.f, 0.f, 0.f, 0.f};

#pragma unroll
    for (int ks = 0; ks < 2; ++ks) {
        bf16x8 a2[2], b2[8];
#pragma unroll
        for (int mt = 0; mt < 2; ++mt) {
            const int row = wv * 32 + mt * 16 + l15;
            a2[mt] = *(const bf16x8*)&sm.mat[row * 8 + ((ks * 4 + q) ^ (row & 7))];
        }
#pragma unroll
        for (int nt = 0; nt < 8; ++nt) {
            const int row = nt * 16 + l15;
            b2[nt] = *(const bf16x8*)&sm.mat[1024 + row * 8 + ((ks * 4 + q) ^ (row & 7))];
        }
#pragma unroll
        for (int mt = 0; mt < 2; ++mt)
#pragma unroll
            for (int nt = 0; nt < 8; ++nt)
                p[mt][nt] = __builtin_amdgcn_mfma_f32_16x16x32_bf16(a2[mt], b2[nt], p[mt][nt], 0, 0, 0);
    }

    float pw[8];
#pragma unroll
    for (int nt = 0; nt < 8; ++nt) pw[nt] = 0.f;

#pragma unroll
    for (int mt = 0; mt < 2; ++mt) {
#pragma unroll
        for (int rr = 0; rr < 4; ++rr) {
            const int srow = wv * 32 + mt * 16 + q * 4 + rr;
            float mx = p[mt][0][rr];
#pragma unroll
            for (int nt = 1; nt < 8; ++nt) mx = fmaxf(mx, p[mt][nt][rr]);
#pragma unroll
            for (int off = 1; off < 16; off <<= 1) mx = fmaxf(mx, __shfl_xor(mx, off));
            float e[8];
            float l = 0.f;
#pragma unroll
            for (int nt = 0; nt < 8; ++nt) {
                e[nt] = __expf((p[mt][nt][rr] - mx) * 0.125f);
                l += e[nt];
            }
#pragma unroll
            for (int off = 1; off < 16; off <<= 1) l += __shfl_xor(l, off);
            const float c = Wo[srow] / l;
#pragma unroll
            for (int nt = 0; nt < 8; ++nt) pw[nt] = fmaf(c, e[nt], pw[nt]);
        }
    }
#pragma unroll
    for (int nt = 0; nt < 8; ++nt) {
        pw[nt] += __shfl_xor(pw[nt], 16);
        pw[nt] += __shfl_xor(pw[nt], 32);
    }
    if (q == 0) {
#pragma unroll
        for (int nt = 0; nt < 8; ++nt) sm.wpart[wv][nt * 16 + l15] = pw[nt];
    }
    __syncthreads();
    if (tid < S)
        sm.wfin[tid] = sm.wpart[0][tid] + sm.wpart[1][tid] + sm.wpart[2][tid] + sm.wpart[3][tid];
    __syncthreads();

    {
        const int dd   = tid >> 2;
        const int part = tid & 3;
        const float* xv = xb + (size_t)(h * D + dd) * S + part * 32;
        float a5 = 0.f;
#pragma unroll 8
        for (int t = 0; t < 32; ++t) a5 = fmaf(sm.wfin[part * 32 + t], xv[t], a5);
        a5 += __shfl_xor(a5, 1);
        a5 += __shfl_xor(a5, 2);
        if (part == 0) out[(size_t)b * F + h * D + dd] = a5 + bo[0];
    }
}

extern "C" void kernel_launch(void* const* d_in, const int* in_sizes, int n_in,
                              void* d_out, int out_size, void* d_ws, size_t ws_size,
                              hipStream_t stream) {
    const float* x  = (const float*)d_in[0];
    const float* Wq = (const float*)d_in[1];
    const float* bq = (const float*)d_in[2];
    const float* Wk = (const float*)d_in[3];
    const float* bk = (const float*)d_in[4];
    const float* Wo = (const float*)d_in[5];
    const float* bo = (const float*)d_in[6];
    float* out = (float*)d_out;

    if (ws_size >= WS_NEED) {
        uint4* xsp = (uint4*)d_ws;
        uint4* wbp = (uint4*)((char*)d_ws + XS_UNITS * 16);
        static bool attr_done = false;
        if (!attr_done) {
            (void)hipFuncSetAttribute(reinterpret_cast<const void*>(attn_main),
                                      hipFuncAttributeMaxDynamicSharedMemorySize, MAIN_LDS_BYTES);
            attr_done = true;
        }
        prep<<<dim3(4096 + 256), dim3(256), 0, stream>>>(x, Wq, Wk, xsp, wbp);
        attn_main<<<dim3(1024), dim3(512), MAIN_LDS_BYTES, stream>>>(x, xsp, wbp, bq, bk, Wo, bo, out);
    } else {
        attn_fallback<<<dim3(256 * H), dim3(256), 0, stream>>>(x, Wq, bq, Wk, bk, Wo, bo, out);
    }
}

// Round 7
// 347.801 us; speedup vs baseline: 1.0222x; 1.0222x over previous
//
#include <hip/hip_runtime.h>

#define F 1024
#define S 128
#define H 16
#define D 64
#define NCHUNK 16    // 1024 / 64; one chunk = one BK=64 K-tile (2048 units of 16B)

typedef short bf16x8 __attribute__((ext_vector_type(8)));
typedef float f32x4  __attribute__((ext_vector_type(4)));

// ws: xs2[128 bg][16 ch][2048 units] (B-tiles: rows = 2 batches' s, k-major)
//     wb2[ 8 hg][16 ch][2048 units] (A-tiles: rows = 2 heads' [Wq;Wk], k-major)
// unit(kc,row) = kc*256 + row ; kc in [0,8) (8 bf16 of k each), row in [0,256)
#define XS_UNITS ((size_t)128 * NCHUNK * 2048)
#define WB_UNITS ((size_t)8 * NCHUNK * 2048)
#define WS_NEED ((XS_UNITS + WB_UNITS) * 16)

#define MAIN_LDS_BYTES (8192 * 16 + 8 * 128 * 4 + 128 * 4)

__device__ __forceinline__ unsigned short f2bf(float f) {
    unsigned u = __float_as_uint(f);
    u += 0x7fffu + ((u >> 16) & 1u);   // round-to-nearest-even
    return (unsigned short)(u >> 16);
}

__device__ __forceinline__ uint4 pack8(const float* f) {
    uint4 u;
    u.x = (unsigned)f2bf(f[0]) | ((unsigned)f2bf(f[1]) << 16);
    u.y = (unsigned)f2bf(f[2]) | ((unsigned)f2bf(f[3]) << 16);
    u.z = (unsigned)f2bf(f[4]) | ((unsigned)f2bf(f[5]) << 16);
    u.w = (unsigned)f2bf(f[6]) | ((unsigned)f2bf(f[7]) << 16);
    return u;
}

typedef __attribute__((address_space(1))) const unsigned int as1_u32;
typedef __attribute__((address_space(3))) unsigned int as3_u32;

__device__ __forceinline__ void async_cp16(const uint4* g, uint4* l) {
    __builtin_amdgcn_global_load_lds((as1_u32*)g, (as3_u32*)l, 16, 0, 0);
}

__device__ __forceinline__ void bar()   { __builtin_amdgcn_s_barrier(); }
__device__ __forceinline__ void sb0()   { __builtin_amdgcn_sched_barrier(0); }

template<int N> __device__ __forceinline__ void vmw() {
    asm volatile("s_waitcnt vmcnt(%0)" :: "n"(N));
}

// ---------------- prep: fp32 -> bf16, k-major tiles; direct coalesced transpose (no LDS) ----------------
__global__ void prep(const float* __restrict__ x,
                     const float* __restrict__ Wq,
                     const float* __restrict__ Wk,
                     uint4* __restrict__ xs,
                     uint4* __restrict__ wb)
{
    const int tid = threadIdx.x;
    const int blk = blockIdx.x;
    if (blk < 4096) {
        // x tile: (b, ch). unit (kc, s) <- x[b][ch*64 + kc*8 + jj][s], jj=0..7.
        const int b = blk >> 4, ch = blk & 15;
        const float* xb = x + ((size_t)b * F + ch * 64) * S;
        uint4* dst = xs + ((size_t)(b >> 1) * NCHUNK + ch) * 2048 + (b & 1) * 128;
#pragma unroll
        for (int j = 0; j < 4; ++j) {
            const int u  = tid + j * 256;
            const int kc = u >> 7;
            const int s  = u & 127;
            const float* rp = xb + (size_t)(kc * 8) * S + s;
            float f[8];
#pragma unroll
            for (int jj = 0; jj < 8; ++jj) f[jj] = rp[jj * S];
            dst[kc * 256 + s] = pack8(f);
        }
    } else {
        // W tile: (h, ch) -> unit = kc*256 + (h&1)*128 + m ; m<64 -> Wq row, else Wk row
        const int blk2 = blk - 4096;
        const int h = blk2 >> 4, ch = blk2 & 15;
        uint4* dst = wb + ((size_t)(h >> 1) * NCHUNK + ch) * 2048 + (h & 1) * 128;
#pragma unroll
        for (int j = 0; j < 4; ++j) {
            const int u  = tid + j * 256;
            const int kc = u >> 7;
            const int m  = u & 127;
            const float* srcp = (m < 64)
                ? (Wq + (size_t)(h * D + m) * F + ch * 64 + kc * 8)
                : (Wk + (size_t)(h * D + m - 64) * F + ch * 64 + kc * 8);
            float f[8];
            float4 a = ((const float4*)srcp)[0];
            float4 c = ((const float4*)srcp)[1];
            f[0] = a.x; f[1] = a.y; f[2] = a.z; f[3] = a.w;
            f[4] = c.x; f[5] = c.y; f[6] = c.z; f[7] = c.w;
            dst[kc * 256 + m] = pack8(f);
        }
    }
}

// ---------------- main kernel: BK=64, 2-buffer, 1-barrier-per-tile, anti-phased k-halves ----------------
// buf b = units [b*4096, +4096): A in [0,2048) (kc*256+row), B in [2048,4096).
// Half h (h=0: kc 0..3, h=1: kc 4..7): 12 ds_read_b128 + 32 MFMA per wave.
__device__ __forceinline__ void halfstep(const uint4* mat, int bufbase, int h,
                                         int wm, int wn, int q, int l15,
                                         f32x4 (&acc)[8][4])
{
    const int kq = (h * 4 + q) * 256;
    const int ab = bufbase + kq + wm * 128 + l15;
    const int bb = bufbase + 2048 + kq + wn * 64 + l15;
    bf16x8 b[4], a[8];
#pragma unroll
    for (int j = 0; j < 4; ++j) b[j] = *(const bf16x8*)&mat[bb + j * 16];
#pragma unroll
    for (int i = 0; i < 8; ++i) a[i] = *(const bf16x8*)&mat[ab + i * 16];
    __builtin_amdgcn_s_setprio(1);
#pragma unroll
    for (int i = 0; i < 8; ++i)
#pragma unroll
        for (int j = 0; j < 4; ++j)
            acc[i][j] = __builtin_amdgcn_mfma_f32_16x16x32_bf16(a[i], b[j], acc[i][j], 0, 0, 0);
    __builtin_amdgcn_s_setprio(0);
}

// Ledger: stage(t+1) issued at tile-t start into buf CUR^1 (holds t-1, whose reads all
// completed before tile-(t-1)'s end barrier). vmcnt(0) at tile end is ~free (loads had a
// full tile to land) and the barrier publishes buf CUR^1 for tile t+1.
// Anti-phase: wm=0 waves do halves [0,1], wm=1 waves [1,0] -> the (wm0,wm1) wave pair on
// each SIMD overlaps one wave's ds_reads with the other's MFMAs; within a wave, half-2's
// reads are independent of half-1's MFMAs (no barrier between) so the compiler overlaps.
template<int CUR, bool DOSTAGE>
__device__ __forceinline__ void ktile64(uint4* mat, const uint4* wbase, const uint4* xbase,
                                        int t, int wv, int lane, int wm, int wn, int q, int l15,
                                        f32x4 (&acc)[8][4])
{
    if constexpr (DOSTAGE) {
        uint4* la = mat + (CUR ^ 1) * 4096;
        const uint4* ga = wbase + (size_t)(t + 1) * 2048;
        const uint4* gb = xbase + (size_t)(t + 1) * 2048;
#pragma unroll
        for (int r = 0; r < 4; ++r) {
            async_cp16(ga + r * 512 + wv * 64 + lane, la + r * 512 + wv * 64);
            async_cp16(gb + r * 512 + wv * 64 + lane, la + 2048 + r * 512 + wv * 64);
        }
    }
    sb0();
    const int bufbase = CUR * 4096;
    halfstep(mat, bufbase, wm,     wm, wn, q, l15, acc);
    halfstep(mat, bufbase, wm ^ 1, wm, wn, q, l15, acc);
    sb0();
    vmw<0>(); bar(); sb0();
}

// ---------------- main: 256x256x1024 GEMM (2 heads x 2 batches) + pair-parallel attention epilogue ----------------
__launch_bounds__(512, 2)
__global__ void attn_main(const float* __restrict__ x,
                          const uint4* __restrict__ xs,
                          const uint4* __restrict__ wb,
                          const float* __restrict__ bq,
                          const float* __restrict__ bk,
                          const float* __restrict__ Wo,
                          const float* __restrict__ bo,
                          float* __restrict__ out)
{
    (void)x;
    extern __shared__ char smraw[];
    uint4* mat   = (uint4*)smraw;                       // 8192 units = 2 bufs x (A 2048 + B 2048)
    float* wpart = (float*)(smraw + 8192 * 16);         // [8][128]

    const int tid  = threadIdx.x;
    const int lane = tid & 63;
    const int wv   = tid >> 6;
    const int l15  = lane & 15;
    const int q    = lane >> 4;
    const int wm   = wv >> 2;      // 2 waves rows
    const int wn   = wv & 3;       // 4 waves cols

    // XCD-aware swizzle: 1024 blocks, 8 XCDs; per XCD 16 bg x 8 hg
    const int g    = blockIdx.x;
    const int xcd  = g & 7;
    const int slot = g >> 3;
    const int bg   = xcd * 16 + (slot & 15);   // batch-pair [0,128)
    const int hg   = slot >> 4;                // head-pair  [0,8)

    const uint4* wbase = wb + (size_t)hg * NCHUNK * 2048;
    const uint4* xbase = xs + (size_t)bg * NCHUNK * 2048;

    f32x4 acc[8][4];
#pragma unroll
    for (int mi = 0; mi < 8; ++mi)
#pragma unroll
        for (int ni = 0; ni < 4; ++ni) acc[mi][ni] = (f32x4){0.f, 0.f, 0.f, 0.f};

    // prologue: stage tile 0 into buf 0; drain; publish.
    {
#pragma unroll
        for (int r = 0; r < 4; ++r) {
            async_cp16(wbase + r * 512 + wv * 64 + lane, mat + r * 512 + wv * 64);
            async_cp16(xbase + r * 512 + wv * 64 + lane, mat + 2048 + r * 512 + wv * 64);
        }
        vmw<0>();
        bar(); sb0();
    }

#pragma unroll 1
    for (int i = 0; i < 7; ++i) {
        ktile64<0, true>(mat, wbase, xbase, 2 * i,     wv, lane, wm, wn, q, l15, acc);
        ktile64<1, true>(mat, wbase, xbase, 2 * i + 1, wv, lane, wm, wn, q, l15, acc);
    }
    ktile64<0, true >(mat, wbase, xbase, 14, wv, lane, wm, wn, q, l15, acc);
    ktile64<1, false>(mat, wbase, xbase, 15, wv, lane, wm, wn, q, l15, acc);

    __syncthreads();

    // C-write: +bias, bf16, write 4 combos' Qs/Ks into LDS (combo c, 2048 units each)
    {
        unsigned short* m16 = (unsigned short*)mat;
        const int hglobw = hg * 2 + wm;
#pragma unroll
        for (int rt = 0; rt < 8; ++rt) {
            const int mh0   = rt * 16 + q * 4;          // rows mh0..mh0+3 (within head's [Wq;Wk])
            const int d0    = mh0 & 63;
            const int kbase = (mh0 < 64) ? 0 : 1024;
            float bias4[4];
#pragma unroll
            for (int rr = 0; rr < 4; ++rr)
                bias4[rr] = (mh0 < 64) ? bq[hglobw * D + d0 + rr] : bk[hglobw * D + d0 + rr];
#pragma unroll
            for (int ct = 0; ct < 4; ++ct) {
                const int col = wn * 64 + ct * 16 + l15;
                const int bj  = col >> 7;
                const int s   = col & 127;
                const int c   = wm * 2 + bj;
                unsigned long long pv = 0;
#pragma unroll
                for (int rr = 0; rr < 4; ++rr)
                    pv |= (unsigned long long)f2bf(acc[rt][ct][rr] + bias4[rr]) << (16 * rr);
                const int unit = c * 2048 + kbase + s * 8 + ((d0 >> 3) ^ (s & 7));
                *(unsigned long long*)&m16[unit * 8 + (d0 & 7)] = pv;   // 8B-aligned (d0&7 in {0,4})
            }
        }
    }
    __syncthreads();

    // ---- pair-parallel epilogue: waves {2c,2c+1} own combo c; all combos concurrent ----
    const int ce   = ((wv >> 2) << 1) | ((wv >> 1) & 1);   // this wave's combo
    const int half = wv & 1;                               // s-row half within combo
    const int qb = ce * 2048;
    const int kb = ce * 2048 + 1024;
    const int bglob = bg * 2 + (ce & 1);
    const int hglob = hg * 2 + (ce >> 1);

    // phase 2: scores for s-rows [half*64, +64), all 128 t
    f32x4 p[4][8];
#pragma unroll
    for (int mt = 0; mt < 4; ++mt)
#pragma unroll
        for (int nt = 0; nt < 8; ++nt) p[mt][nt] = (f32x4){0.f, 0.f, 0.f, 0.f};
#pragma unroll
    for (int ks = 0; ks < 2; ++ks) {
        const int kcq = ks * 4 + q;
        bf16x8 a2[4], b2[8];
#pragma unroll
        for (int mt = 0; mt < 4; ++mt) {
            const int row = half * 64 + mt * 16 + l15;
            a2[mt] = *(const bf16x8*)&mat[qb + row * 8 + (kcq ^ (row & 7))];
        }
#pragma unroll
        for (int nt = 0; nt < 8; ++nt) {
            const int trow = nt * 16 + l15;
            b2[nt] = *(const bf16x8*)&mat[kb + trow * 8 + (kcq ^ (trow & 7))];
        }
#pragma unroll
        for (int mt = 0; mt < 4; ++mt)
#pragma unroll
            for (int nt = 0; nt < 8; ++nt)
                p[mt][nt] = __builtin_amdgcn_mfma_f32_16x16x32_bf16(a2[mt], b2[nt], p[mt][nt], 0, 0, 0);
    }

    // phase-5 loads issued EARLY (hidden under softmax): coalesced uint4 from xs, chunk ch = hglob
    const int ell = half * 64 + lane;
    const int kc5 = ell >> 4;
    const int sg5 = ell & 15;
    const uint4* xsrc = xbase + (size_t)hglob * 2048 + kc5 * 256 + (ce & 1) * 128 + sg5 * 8;
    uint4 xu[8];
#pragma unroll
    for (int jj = 0; jj < 8; ++jj) xu[jj] = xsrc[jj];

    // phases 3+4: softmax (no max-sub; scores ~N(0,1), clamp insurance) + fold Wo
    float pw[8];
#pragma unroll
    for (int nt = 0; nt < 8; ++nt) pw[nt] = 0.f;
#pragma unroll
    for (int mt = 0; mt < 4; ++mt) {
#pragma unroll
        for (int rr = 0; rr < 4; ++rr) {
            const int srow = half * 64 + mt * 16 + q * 4 + rr;
            float e[8];
            float l = 0.f;
#pragma unroll
            for (int nt = 0; nt < 8; ++nt) {
                e[nt] = __expf(fminf(p[mt][nt][rr] * 0.125f, 80.f));   // 1/TEMP = 1/8
                l += e[nt];
            }
#pragma unroll
            for (int off = 1; off < 16; off <<= 1) l += __shfl_xor(l, off);
            const float cw = Wo[srow] / l;
#pragma unroll
            for (int nt = 0; nt < 8; ++nt) pw[nt] = fmaf(cw, e[nt], pw[nt]);
        }
    }
#pragma unroll
    for (int nt = 0; nt < 8; ++nt) {
        pw[nt] += __shfl_xor(pw[nt], 16);
        pw[nt] += __shfl_xor(pw[nt], 32);
    }
    if (q == 0) {
#pragma unroll
        for (int nt = 0; nt < 8; ++nt) wpart[wv * 128 + nt * 16 + l15] = pw[nt];
    }
    __syncthreads();

    // phase 5: out[bglob, hglob*64 + kc5*8 + e] = sum_s w[s] * x_bf16 + bo  (x from regs)
    {
        const float* w0 = wpart + 2 * ce * 128;
        const float* w1 = w0 + 128;
        float acc8[8];
#pragma unroll
        for (int e = 0; e < 8; ++e) acc8[e] = 0.f;
#pragma unroll
        for (int jj = 0; jj < 8; ++jj) {
            const int s = sg5 * 8 + jj;
            const float w = w0[s] + w1[s];
            const unsigned* du = (const unsigned*)&xu[jj];
#pragma unroll
            for (int dw = 0; dw < 4; ++dw) {
                const unsigned v = du[dw];
                acc8[dw * 2 + 0] = fmaf(__uint_as_float(v << 16), w, acc8[dw * 2 + 0]);
                acc8[dw * 2 + 1] = fmaf(__uint_as_float(v & 0xffff0000u), w, acc8[dw * 2 + 1]);
            }
        }
#pragma unroll
        for (int e = 0; e < 8; ++e) {
#pragma unroll
            for (int off = 1; off < 16; off <<= 1)
                acc8[e] += __shfl_xor(acc8[e], off);
        }
        if (sg5 < 8)
            out[(size_t)bglob * F + hglob * D + kc5 * 8 + sg5] = acc8[sg5] + bo[0];
    }
}

// ---------------- fallback (self-contained) if ws too small ----------------
struct SmemT {
    uint4 mat[2048];
    float wpart[4][S];
    float wfin[S];
};

__launch_bounds__(256, 4)
__global__ void attn_fallback(const float* __restrict__ x,
                              const float* __restrict__ Wq,
                              const float* __restrict__ bq,
                              const float* __restrict__ Wk,
                              const float* __restrict__ bk,
                              const float* __restrict__ Wo,
                              const float* __restrict__ bo,
                              float* __restrict__ out)
{
    __shared__ SmemT sm;
    const int tid  = threadIdx.x;
    const int lane = tid & 63;
    const int wv   = tid >> 6;
    const int l15  = lane & 15;
    const int q    = lane >> 4;

    const int g    = blockIdx.x;
    const int xcd  = g & 7;
    const int slot = g >> 3;
    const int hg   = slot >> 7;
    const int r0   = slot & 127;
    const int b    = xcd * 32 + (r0 >> 2);
    const int h    = hg * 4 + (r0 & 3);

    const float* xb  = x  + (size_t)b * (F * S);
    const float* wqh = Wq + (size_t)h * D * F;
    const float* wkh = Wk + (size_t)h * D * F;

    const int m0 = (wv & 1) * 64;
    const int n0 = (wv >> 1) * 64;

    f32x4 acc[4][4];
#pragma unroll
    for (int mt = 0; mt < 4; ++mt)
#pragma unroll
        for (int nt = 0; nt < 4; ++nt) acc[mt][nt] = (f32x4){0.f, 0.f, 0.f, 0.f};

    const int mq  = tid >> 2;
    const int kq  = tid & 3;
    const int s0x = (tid & 63) * 2;
    const int iq  = tid >> 6;

    for (int ch = 0; ch < NCHUNK; ++ch) {
        const int c0 = ch * 64;
        __syncthreads();
        {
            const int key = mq & 7;
            float f[16];
            const float4* srcq = (const float4*)(wqh + (size_t)mq * F + (c0 + kq * 16));
#pragma unroll
            for (int j = 0; j < 4; ++j) {
                float4 v = srcq[j];
                f[4*j] = v.x; f[4*j+1] = v.y; f[4*j+2] = v.z; f[4*j+3] = v.w;
            }
            sm.mat[mq * 8 + ((kq * 2    ) ^ key)] = pack8(f);
            sm.mat[mq * 8 + ((kq * 2 + 1) ^ key)] = pack8(f + 8);
            const float4* srck = (const float4*)(wkh + (size_t)mq * F + (c0 + kq * 16));
#pragma unroll
            for (int j = 0; j < 4; ++j) {
                float4 v = srck[j];
                f[4*j] = v.x; f[4*j+1] = v.y; f[4*j+2] = v.z; f[4*j+3] = v.w;
            }
            sm.mat[(64 + mq) * 8 + ((kq * 2    ) ^ key)] = pack8(f);
            sm.mat[(64 + mq) * 8 + ((kq * 2 + 1) ^ key)] = pack8(f + 8);
        }
        {
            const float* src = xb + (size_t)(c0 + iq * 16) * S + s0x;
            float fa[8], fb[8];
#pragma unroll
            for (int grp = 0; grp < 2; ++grp) {
#pragma unroll
                for (int j = 0; j < 8; ++j) {
                    float2 v = *(const float2*)(src + (size_t)(grp * 8 + j) * S);
                    fa[j] = v.x; fb[j] = v.y;
                }
                const int kc = iq * 2 + grp;
                sm.mat[1024 + (s0x    ) * 8 + (kc ^ ((s0x    ) & 7))] = pack8(fa);
                sm.mat[1024 + (s0x + 1) * 8 + (kc ^ ((s0x + 1) & 7))] = pack8(fb);
            }
        }
        __syncthreads();
#pragma unroll
        for (int ks = 0; ks < 2; ++ks) {
            bf16x8 af[4], br[4];
#pragma unroll
            for (int mt = 0; mt < 4; ++mt) {
                const int row = m0 + mt * 16 + l15;
                af[mt] = *(const bf16x8*)&sm.mat[row * 8 + ((ks * 4 + q) ^ (row & 7))];
            }
#pragma unroll
            for (int nt = 0; nt < 4; ++nt) {
                const int row = n0 + nt * 16 + l15;
                br[nt] = *(const bf16x8*)&sm.mat[1024 + row * 8 + ((ks * 4 + q) ^ (row & 7))];
            }
#pragma unroll
            for (int mt = 0; mt < 4; ++mt)
#pragma unroll
                for (int nt = 0; nt < 4; ++nt)
                    acc[mt][nt] = __builtin_amdgcn_mfma_f32_16x16x32_bf16(
                        af[mt], br[nt], acc[mt][nt], 0, 0, 0);
        }
    }

    __syncthreads();
    {
        unsigned short* m16 = (unsigned short*)sm.mat;
#pragma unroll
        for (int mt = 0; mt < 4; ++mt) {
#pragma unroll
            for (int rr = 0; rr < 4; ++rr) {
                const int m = m0 + mt * 16 + q * 4 + rr;
                const int d = m & 63;
                const float bias = (m < 64) ? bq[h * D + d] : bk[h * D + d];
                const int base = (m < 64) ? 0 : 8192;
#pragma unroll
                for (int nt = 0; nt < 4; ++nt) {
                    const int s = n0 + nt * 16 + l15;
                    const float v = acc[mt][nt][rr] + bias;
                    const int unit = s * 8 + (((d >> 3)) ^ (s & 7));
                    m16[base + unit * 8 + (d & 7)] = f2bf(v);
                }
            }
        }
    }
    __syncthreads();

    f32x4 p[2][8];
#pragma unroll
    for (int mt = 0; mt < 2; ++mt)
#pragma unroll
        for (int nt = 0; nt < 8; ++nt) p[mt][nt] = (f32x4){0.f, 0.f, 0.f, 0.f};

#pragma unroll
    for (int ks = 0; ks < 2; ++ks) {
        bf16x8 a2[2], b2[8];
#pragma unroll
        for (int mt = 0; mt < 2; ++mt) {
            const int row = wv * 32 + mt * 16 + l15;
            a2[mt] = *(const bf16x8*)&sm.mat[row * 8 + ((ks * 4 + q) ^ (row & 7))];
        }
#pragma unroll
        for (int nt = 0; nt < 8; ++nt) {
            const int row = nt * 16 + l15;
            b2[nt] = *(const bf16x8*)&sm.mat[1024 + row * 8 + ((ks * 4 + q) ^ (row & 7))];
        }
#pragma unroll
        for (int mt = 0; mt < 2; ++mt)
#pragma unroll
            for (int nt = 0; nt < 8; ++nt)
                p[mt][nt] = __builtin_amdgcn_mfma_f32_16x16x32_bf16(a2[mt], b2[nt], p[mt][nt], 0, 0, 0);
    }

    float pw[8];
#pragma unroll
    for (int nt = 0; nt < 8; ++nt) pw[nt] = 0.f;

#pragma unroll
    for (int mt = 0; mt < 2; ++mt) {
#pragma unroll
        for (int rr = 0; rr < 4; ++rr) {
            const int srow = wv * 32 + mt * 16 + q * 4 + rr;
            float mx = p[mt][0][rr];
#pragma unroll
            for (int nt = 1; nt < 8; ++nt) mx = fmaxf(mx, p[mt][nt][rr]);
#pragma unroll
            for (int off = 1; off < 16; off <<= 1) mx = fmaxf(mx, __shfl_xor(mx, off));
            float e[8];
            float l = 0.f;
#pragma unroll
            for (int nt = 0; nt < 8; ++nt) {
                e[nt] = __expf((p[mt][nt][rr] - mx) * 0.125f);
                l += e[nt];
            }
#pragma unroll
            for (int off = 1; off < 16; off <<= 1) l += __shfl_xor(l, off);
            const float c = Wo[srow] / l;
#pragma unroll
            for (int nt = 0; nt < 8; ++nt) pw[nt] = fmaf(c, e[nt], pw[nt]);
        }
    }
#pragma unroll
    for (int nt = 0; nt < 8; ++nt) {
        pw[nt] += __shfl_xor(pw[nt], 16);
        pw[nt] += __shfl_xor(pw[nt], 32);
    }
    if (q == 0) {
#pragma unroll
        for (int nt = 0; nt < 8; ++nt) sm.wpart[wv][nt * 16 + l15] = pw[nt];
    }
    __syncthreads();
    if (tid < S)
        sm.wfin[tid] = sm.wpart[0][tid] + sm.wpart[1][tid] + sm.wpart[2][tid] + sm.wpart[3][tid];
    __syncthreads();

    {
        const int dd   = tid >> 2;
        const int part = tid & 3;
        const float* xv = xb + (size_t)(h * D + dd) * S + part * 32;
        float a5 = 0.f;
#pragma unroll 8
        for (int t = 0; t < 32; ++t) a5 = fmaf(sm.wfin[part * 32 + t], xv[t], a5);
        a5 += __shfl_xor(a5, 1);
        a5 += __shfl_xor(a5, 2);
        if (part == 0) out[(size_t)b * F + h * D + dd] = a5 + bo[0];
    }
}

extern "C" void kernel_launch(void* const* d_in, const int* in_sizes, int n_in,
                              void* d_out, int out_size, void* d_ws, size_t ws_size,
                              hipStream_t stream) {
    const float* x  = (const float*)d_in[0];
    const float* Wq = (const float*)d_in[1];
    const float* bq = (const float*)d_in[2];
    const float* Wk = (const float*)d_in[3];
    const float* bk = (const float*)d_in[4];
    const float* Wo = (const float*)d_in[5];
    const float* bo = (const float*)d_in[6];
    float* out = (float*)d_out;

    if (ws_size >= WS_NEED) {
        uint4* xsp = (uint4*)d_ws;
        uint4* wbp = (uint4*)((char*)d_ws + XS_UNITS * 16);
        static bool attr_done = false;
        if (!attr_done) {
            (void)hipFuncSetAttribute(reinterpret_cast<const void*>(attn_main),
                                      hipFuncAttributeMaxDynamicSharedMemorySize, MAIN_LDS_BYTES);
            attr_done = true;
        }
        prep<<<dim3(4096 + 256), dim3(256), 0, stream>>>(x, Wq, Wk, xsp, wbp);
        attn_main<<<dim3(1024), dim3(512), MAIN_LDS_BYTES, stream>>>(x, xsp, wbp, bq, bk, Wo, bo, out);
    } else {
        attn_fallback<<<dim3(256 * H), dim3(256), 0, stream>>>(x, Wq, bq, Wk, bk, Wo, bo, out);
    }
}